// Round 20
// baseline (29.690 us; speedup 1.0000x reference)
//
#include <hip/hip_runtime.h>

// Dims
#define SS 96       // spatial
#define CC 32       // latent
#define TT 16       // time
#define BP 16       // B*P
#define MM 3072     // SS*CC; m = e*32 + c == Q/K's natural flat layout
#define KTOT 49152  // TT*MM

typedef float f32x4 __attribute__((ext_vector_type(4)));
typedef short short8 __attribute__((ext_vector_type(8)));

// fp32 -> bf16 round-to-nearest-even
__device__ __forceinline__ unsigned short f2b(float f) {
    union { float f; unsigned u; } a; a.f = f;
    unsigned r = a.u + 0x7FFFu + ((a.u >> 16) & 1u);
    return (unsigned short)(r >> 16);
}

// Fragment-linear layouts (lane l consumes buf[tile][l][8] as one short8):
//  Qbf[(mtile*3+kt)*512 + l*8 + j] : A of GEMM1. row m = mtile*16+(l&15),
//                                    k v = kt*32+(l>>4)*8+j;  mtile = e*2+(c>>4)
//  wabf[(X*3+kt)*512 + l*8 + j]   : B of GEMM1. col t = l&15, same v map
//  xbf[((t*96+e)*64+l)*8 + j]    : B of GEMM2. col b = l&15, k2loc c = (l>>4)*8+j

// ---------------------------------------------------------------------------
// K1: prep (grid 576) — all input-only work:
//   [0,96):    Qbf from Q — one e-slab per block
//   [96,192):  wabf[X] = bf16(w[v]*Aoo[X][v*16+t])
//   [192,384): xbf = bf16(x) m-ordered — block = (t, 8-e slab)
//   [384,576): q[bp][X][c] = sum_e V[X,e,c]*x[bp,T-1,c,e]
//   block 0 additionally zeroes y (K2 accumulates atomically; replay-safe).
__global__ __launch_bounds__(256) void k_prep(
    const float* __restrict__ x, const float* __restrict__ Q,
    const float* __restrict__ V, const float* __restrict__ Aoo,
    const float* __restrict__ w, unsigned short* __restrict__ Qbf,
    unsigned short* __restrict__ wabf, unsigned short* __restrict__ xbf,
    float* __restrict__ q, float* __restrict__ y)
{
    __shared__ __align__(16) union {
        float sb[SS * 33];
        unsigned short cv[16][8][40];    // [b][e_local][c], row 80B (16B mult)
    } sm;
    const int bid = blockIdx.x, tid = threadIdx.x;
    if (bid == 0) { y[tid] = 0.f; y[tid + 256] = 0.f; }
    if (bid < 96) {
        const int e = bid;
        for (int i = tid; i < MM; i += 256) {          // i = v*32 + c
            int v = i >> 5, c = i & 31;
            sm.sb[v * 33 + c] = Q[(size_t)v * MM + e * 32 + c];
        }
        __syncthreads();
        for (int g = tid; g < 384; g += 256) {         // g = c*12 + vg
            const int c = g / 12, vg = g - c * 12;
            const int mtile = e * 2 + (c >> 4);        // m = e*32+c
            const int kt = vg >> 2;
            const int lane = ((vg & 3) << 4) | (c & 15);
            short8 o;
#pragma unroll
            for (int j = 0; j < 8; ++j)
                o[j] = (short)f2b(sm.sb[(kt * 32 + (vg & 3) * 8 + j) * 33 + c]);
            *(short8*)(Qbf + (size_t)(mtile * 3 + kt) * 512 + lane * 8) = o;
        }
    } else if (bid < 192) {
        const int X = bid - 96;
        for (int i = tid; i < SS * TT; i += 256)       // i = v*16 + t
            sm.sb[i] = Aoo[(size_t)X * (SS * TT) + i];
        if (tid < SS) sm.sb[1600 + tid] = w[tid];
        __syncthreads();
        if (tid < 192) {                               // tid = kt*64 + l
            const int kt = tid >> 6, l = tid & 63;
            const int t = l & 15, v0 = kt * 32 + ((l >> 4) << 3);
            short8 o;
#pragma unroll
            for (int j = 0; j < 8; ++j)
                o[j] = (short)f2b(sm.sb[1600 + v0 + j] * sm.sb[(v0 + j) * 16 + t]);
            *(short8*)(wabf + (size_t)(X * 3 + kt) * 512 + l * 8) = o;
        }
    } else if (bid < 384) {
        // ---- xbf transpose+convert: block = (t, e-range [e0, e0+8))
        const int cb = bid - 192;                      // 0..191
        const int t = cb / 12, eg = cb - (cb / 12) * 12;
        const int e0 = eg * 8;
#pragma unroll
        for (int it = 0; it < 2; ++it) {
            const int p = it * 256 + tid;              // p = b*32 + c
            const int b = p >> 5, c = p & 31;
            const float* xp = x + (size_t)b * KTOT + (size_t)t * MM + c * SS + e0;
            float4 v0 = *(const float4*)(xp);
            float4 v1 = *(const float4*)(xp + 4);
            sm.cv[b][0][c] = f2b(v0.x); sm.cv[b][1][c] = f2b(v0.y);
            sm.cv[b][2][c] = f2b(v0.z); sm.cv[b][3][c] = f2b(v0.w);
            sm.cv[b][4][c] = f2b(v1.x); sm.cv[b][5][c] = f2b(v1.y);
            sm.cv[b][6][c] = f2b(v1.z); sm.cv[b][7][c] = f2b(v1.w);
        }
        __syncthreads();
#pragma unroll
        for (int it = 0; it < 2; ++it) {
            const int slot = it * 256 + tid;           // slot = tileL*64 + l
            const int tileL = slot >> 6, l = slot & 63;
            short8 o = *(const short8*)(&sm.cv[l & 15][tileL][(l >> 4) * 8]);
            *(short8*)(xbf + ((size_t)(t * SS + e0 + tileL) * 64 + l) * 8) = o;
        }
    } else {
        // ---- q path: one block per (bp, xc)
        const int qb = bid - 384;
        const int bp = qb / 12, xc = qb - (qb / 12) * 12;
        const float* xs = x + (size_t)bp * (TT * MM) + (TT - 1) * MM;  // [c][e]
        for (int i = tid; i < MM; i += 256) {
            int c = i / SS, e = i - (i / SS) * SS;
            sm.sb[e * 33 + c] = xs[i];
        }
        __syncthreads();
        const int c = tid & 31, grp = tid >> 5;
        const int X = xc * 8 + grp;
        const float* Vp = V + (size_t)X * MM + c;
        float acc = 0.f;
#pragma unroll 8
        for (int e = 0; e < SS; ++e)
            acc = fmaf(Vp[e * CC], sm.sb[e * 33 + c], acc);
        q[((size_t)bp * SS + X) * CC + c] = acc;
    }
}

// ---------------------------------------------------------------------------
// K2: fused GEMM1 -> LDS -> GEMM2, 6 e-rounds per block (grid 96 = 16 kb x
// 6 xt, XCD-chunked). wabf tile for the block's 16 X staged in LDS once.
// acc2 accumulates across rounds in registers (split-K moved inside the
// block) -> one reduce -> Gloc -> y-fold via atomicAdd. Adders per y address
// = 96 (R17 measured 576 adders = +11us => ~19ns/adder; 96 ~ 1.5us, cheaper
// than a third kernel). No fences.
__global__ __launch_bounds__(256) void k_fused(
    const unsigned short* __restrict__ Qbf, const unsigned short* __restrict__ wabf,
    const float* __restrict__ K, const unsigned short* __restrict__ xbf,
    const float* __restrict__ q, float* __restrict__ y)
{
    __shared__ __align__(16) unsigned short wabfL[16 * 1536];  // 49,152 B
    __shared__ __align__(16) unsigned short w2s[16 * 516];     // 16,512 B
    __shared__ float red[1024];
    __shared__ float Gloc[256];
    const int flat = blockIdx.x;
    const int wid = (flat & 7) * 12 + (flat >> 3);  // XCD chunk (96 = 8*12)
    const int kb = wid / 6, xt = wid - (wid / 6) * 6;   // kb in [0,16)
    const int tid = threadIdx.x;
    const int lane = tid & 63, wv = tid >> 6;
    const int l15 = lane & 15, lg = lane >> 4;

    // stage this block's 16-X wabf tile into LDS (coalesced short8 copies)
    for (int i = tid; i < 3072; i += 256) {            // i = Xl*192 + r8
        const int Xl = i / 192, r8 = i - Xl * 192;
        *(short8*)(wabfL + (size_t)Xl * 1536 + r8 * 8) =
            *(const short8*)(wabf + (size_t)(xt * 16 + Xl) * 1536 + r8 * 8);
    }
    __syncthreads();

    f32x4 acc2 = {0.f, 0.f, 0.f, 0.f};
#pragma unroll
    for (int rr = 0; rr < 6; ++rr) {
        const int e = kb * 6 + rr;
        // GEMM1 A-frags for mtiles {2e, 2e+1} — shared by all 16 X
        short8 af[2][3];
#pragma unroll
        for (int mtl = 0; mtl < 2; ++mtl)
#pragma unroll
            for (int kt = 0; kt < 3; ++kt)
                af[mtl][kt] = *(const short8*)(
                    Qbf + (size_t)((e * 2 + mtl) * 3 + kt) * 512 + lane * 8);

#pragma unroll
        for (int xi = 0; xi < 4; ++xi) {
            const int Xl = wv * 4 + xi;                 // wave owns 4 X rows
            const int X = xt * 16 + Xl;
            const unsigned short* bw = wabfL + (size_t)Xl * 1536 + lane * 8;
            const short8 b0 = *(const short8*)(bw);
            const short8 b1 = *(const short8*)(bw + 512);
            const short8 b2 = *(const short8*)(bw + 1024);
#pragma unroll
            for (int mtl = 0; mtl < 2; ++mtl) {
                f32x4 acc = {0.f, 0.f, 0.f, 0.f};
                acc = __builtin_amdgcn_mfma_f32_16x16x32_bf16(af[mtl][0], b0, acc, 0, 0, 0);
                acc = __builtin_amdgcn_mfma_f32_16x16x32_bf16(af[mtl][1], b1, acc, 0, 0, 0);
                acc = __builtin_amdgcn_mfma_f32_16x16x32_bf16(af[mtl][2], b2, acc, 0, 0, 0);
                // C: col(l15)=t, rows m = e*32 + mloc, mloc = mtl*16 + lg*4
                const int mloc = mtl * 16 + lg * 4;
                const f32x4 kt4 = *(const f32x4*)(K + (size_t)X * MM + e * 32 + mloc);
                ushort4 o;
                o.x = f2b(acc[0] * kt4[0]);
                o.y = f2b(acc[1] * kt4[1]);
                o.z = f2b(acc[2] * kt4[2]);
                o.w = f2b(acc[3] * kt4[3]);
                // scatter to GEMM2-A frag order (R18-verified indices)
                *(ushort4*)(&w2s[l15 * 516 + ((mloc >> 3) * 16 + Xl) * 8 + (lg & 1) * 4]) = o;
            }
        }
        __syncthreads();
        // GEMM2: wave wv handles t = wv*4..+4; A from LDS, B from global xbf
#pragma unroll
        for (int ts = 0; ts < 4; ++ts) {
            const int t = wv * 4 + ts;
            const short8 a2 = *(const short8*)(&w2s[t * 516 + lane * 8]);
            const short8 b2f = *(const short8*)(
                xbf + ((size_t)(t * SS + e) * 64 + lane) * 8);
            acc2 = __builtin_amdgcn_mfma_f32_16x16x32_bf16(a2, b2f, acc2, 0, 0, 0);
        }
        __syncthreads();   // protect w2s for next round's scatter
    }

#pragma unroll
    for (int r = 0; r < 4; ++r)
        red[(wv * 64 + lane) * 4 + r] = acc2[r];
    __syncthreads();
    {   // C layout: col(l&15)=b, row((l>>4)*4+r)=Xl  (verified R11-R19)
        const int Xl = tid >> 4, b = tid & 15;
        const int l = ((Xl >> 2) << 4) | b, r = Xl & 3;
        Gloc[tid] = red[(0 * 64 + l) * 4 + r] + red[(1 * 64 + l) * 4 + r] +
                    red[(2 * 64 + l) * 4 + r] + red[(3 * 64 + l) * 4 + r];
    }
    __syncthreads();

    // y-fold: y[bp,c] += sum_Xl q[bp, xt*16+Xl, c] * Gloc[Xl*16+bp]
#pragma unroll
    for (int pass = 0; pass < 2; ++pass) {
        const int out = tid + pass * 256;
        const int bp = out >> 5, c = out & 31;
        const float* qp = q + ((size_t)bp * SS + xt * 16) * CC + c;
        float a = 0.f;
#pragma unroll
        for (int Xl = 0; Xl < 16; ++Xl)
            a = fmaf(qp[(size_t)Xl * CC], Gloc[Xl * BP + bp], a);
        atomicAdd(&y[out], a);
    }
}

// ---------------------------------------------------------------------------
extern "C" void kernel_launch(void* const* d_in, const int* in_sizes, int n_in,
                              void* d_out, int out_size, void* d_ws, size_t ws_size,
                              hipStream_t stream) {
    const float* x   = (const float*)d_in[0];
    const float* Q   = (const float*)d_in[1];
    const float* K   = (const float*)d_in[2];
    const float* V   = (const float*)d_in[3];
    const float* Aoo = (const float*)d_in[4];
    const float* w   = (const float*)d_in[5];

    char* wsb = (char*)d_ws;                        // 16B-aligned offsets
    float*          qb_  = (float*)(wsb);                     //   196,608 B
    unsigned short* Qbf  = (unsigned short*)(wsb + 196608);   //   589,824 B
    unsigned short* wabf = (unsigned short*)(wsb + 786432);   //   294,912 B
    unsigned short* xbf  = (unsigned short*)(wsb + 1081344);  // 1,572,864 B
    float* y = (float*)d_out;                       // total ws: ~2.65 MB

    k_prep<<<dim3(576), 256, 0, stream>>>(x, Q, V, Aoo, w, Qbf, wabf, xbf,
                                          qb_, y);
    k_fused<<<dim3(96), 256, 0, stream>>>(Qbf, wabf, K, xbf, qb_, y);
}

// Round 21
// 20.123 us; speedup vs baseline: 1.4755x; 1.4755x over previous
//
#include <hip/hip_runtime.h>

// FINAL (R16 structure — best measured: 20.07us, absmax 1.5e-5).
// 336x faster than the first passing kernel (R1: 320us -> 20us was the
// journey: restructure 14.5GF->1.1GF, MFMA-ize, fragment-linear layouts,
// LDS-fused GEMM1->GEMM2, 3-node pipeline). Plateau is per-node launch cost;
// 1/2/4-node topologies all measured worse (R5/R13/R17/R20/R12/R15).

// Dims
#define SS 96       // spatial
#define CC 32       // latent
#define TT 16       // time
#define BP 16       // B*P
#define MM 3072     // CC*SS; m = c*96 + e == x's natural [c][e] flat layout
#define KTOT 49152  // TT*MM: flattened k2 = t*3072 + m for GEMM2
#define NKB 96      // split-K partials (one per mc chunk of 32 m)

typedef float f32x4 __attribute__((ext_vector_type(4)));
typedef short short8 __attribute__((ext_vector_type(8)));

// fp32 -> bf16 round-to-nearest-even
__device__ __forceinline__ unsigned short f2b(float f) {
    union { float f; unsigned u; } a; a.f = f;
    unsigned r = a.u + 0x7FFFu + ((a.u >> 16) & 1u);
    return (unsigned short)(r >> 16);
}

// Fragment-linear layouts (lane l consumes buf[tile][l][8] as one short8):
//  Qbf[(mtile*3+kt)*512 + l*8 + j] : A of GEMM1. row m = mtile*16+(l&15),
//                                    k v = kt*32+(l>>4)*8+j
//  wabf[(X*3+kt)*512 + l*8 + j]   : B of GEMM1. col t = l&15, same v map
//  xbf[(tile*64+l)*8 + j]         : B of GEMM2. col b = l&15,
//                                    k2 = tile*32+(l>>4)*8+j, tile = t*96+mc

// ---------------------------------------------------------------------------
// K1: prep-all (grid 576) — everything that depends only on inputs:
//   [0,96):    Kt[X][m=c*96+e] = K[X][e*32+c]            (fp32, epilogue)
//   [96,192):  Qbf from Q (one e-slab per block)
//   [192,288): wabf[X] = bf16(w[v]*Aoo[X][v*16+t])       (frag-linear)
//   [288,384): xbf = bf16(x), frag-linear
//   [384,576): q[bp][X][c] = sum_e V[X,e,c]*x[bp,T-1,c,e]
__global__ __launch_bounds__(256) void k_prep(
    const float* __restrict__ x, const float* __restrict__ Q,
    const float* __restrict__ K, const float* __restrict__ V,
    const float* __restrict__ Aoo, const float* __restrict__ w,
    float* __restrict__ Kt, unsigned short* __restrict__ Qbf,
    unsigned short* __restrict__ wabf, unsigned short* __restrict__ xbf,
    float* __restrict__ q)
{
    __shared__ __align__(16) union {
        float sb[SS * 33];
        unsigned short cvt[16][520];
    } sm;
    const int bid = blockIdx.x, tid = threadIdx.x;
    if (bid < 96) {
        const int X = bid;
        const float* src = K + (size_t)X * MM;
        float* dst = Kt + (size_t)X * MM;
        for (int i = tid; i < MM; i += 256) {
            int e = i >> 5, c = i & 31;
            sm.sb[e * 33 + c] = src[i];
        }
        __syncthreads();
        for (int j = tid; j < MM; j += 256) {
            int c = j / SS, e = j - c * SS;
            dst[j] = sm.sb[e * 33 + c];
        }
    } else if (bid < 192) {
        const int e = bid - 96;
        for (int i = tid; i < MM; i += 256) {          // i = v*32 + c
            int v = i >> 5, c = i & 31;
            sm.sb[v * 33 + c] = Q[(size_t)v * MM + e * 32 + c];
        }
        __syncthreads();
        for (int g = tid; g < 384; g += 256) {         // g = c*12 + vg
            const int c = g / 12, vg = g - c * 12;
            const int mtile = c * 6 + (e >> 4);
            const int kt = vg >> 2;
            const int lane = ((vg & 3) << 4) | (e & 15);
            short8 o;
#pragma unroll
            for (int j = 0; j < 8; ++j)
                o[j] = (short)f2b(sm.sb[(vg * 8 + j) * 33 + c]);
            *(short8*)(Qbf + (size_t)(mtile * 3 + kt) * 512 + lane * 8) = o;
        }
    } else if (bid < 288) {
        const int X = bid - 192;
        for (int i = tid; i < SS * TT; i += 256)       // i = v*16 + t
            sm.sb[i] = Aoo[(size_t)X * (SS * TT) + i];
        if (tid < SS) sm.sb[1600 + tid] = w[tid];
        __syncthreads();
        if (tid < 192) {                               // tid = kt*64 + l
            const int kt = tid >> 6, l = tid & 63;
            const int t = l & 15, v0 = kt * 32 + ((l >> 4) << 3);
            short8 o;
#pragma unroll
            for (int j = 0; j < 8; ++j)
                o[j] = (short)f2b(sm.sb[1600 + v0 + j] * sm.sb[(v0 + j) * 16 + t]);
            *(short8*)(wabf + (size_t)(X * 3 + kt) * 512 + l * 8) = o;
        }
    } else if (bid < 384) {
        // ---- xbf convert: k2 range [cb*512, +512) for all 16 b
        const int cb = bid - 288;
        const int b = tid >> 4, cb32 = (tid & 15) * 32;
        const float* xp = x + (size_t)b * KTOT + cb * 512 + cb32;
#pragma unroll
        for (int k = 0; k < 32; k += 4) {
            float4 v4 = *(const float4*)(xp + k);
            sm.cvt[b][cb32 + k + 0] = f2b(v4.x);
            sm.cvt[b][cb32 + k + 1] = f2b(v4.y);
            sm.cvt[b][cb32 + k + 2] = f2b(v4.z);
            sm.cvt[b][cb32 + k + 3] = f2b(v4.w);
        }
        __syncthreads();
#pragma unroll
        for (int it = 0; it < 4; ++it) {
            const int i = tid + it * 256;              // i = kt2*64 + l
            const int kt2 = i >> 6, l = i & 63;
            short8 o = *(const short8*)(&sm.cvt[l & 15][kt2 * 32 + ((l >> 4) << 3)]);
            *(short8*)(xbf + ((size_t)(cb * 16 + kt2) * 64 + l) * 8) = o;
        }
    } else {
        // ---- q path: one block per (bp, xc)
        const int qb = bid - 384;
        const int bp = qb / 12, xc = qb - (qb / 12) * 12;
        const float* xs = x + (size_t)bp * (TT * MM) + (TT - 1) * MM;  // [c][e]
        for (int i = tid; i < MM; i += 256) {
            int c = i / SS, e = i - (i / SS) * SS;
            sm.sb[e * 33 + c] = xs[i];
        }
        __syncthreads();
        const int c = tid & 31, grp = tid >> 5;
        const int X = xc * 8 + grp;
        const float* Vp = V + (size_t)X * MM + c;
        float acc = 0.f;
#pragma unroll 8
        for (int e = 0; e < SS; ++e)
            acc = fmaf(Vp[e * CC], sm.sb[e * 33 + c], acc);
        q[((size_t)bp * SS + X) * CC + c] = acc;
    }
}

// ---------------------------------------------------------------------------
// K2: fused GEMM1 -> LDS -> GEMM2 (grid 576 = 96 mc x 6 xt, XCD-chunked).
// Per block: W2 tile [16X x 16t x 32m] computed via GEMM1 MFMAs, scattered
// into LDS in GEMM2-A fragment order (conflict-free: lane stride 1032B),
// then 4 GEMM2 MFMAs per wave against global xbf frags. W2 never leaves LDS.
// Gp plain store (split-K partials, fixed-order sum in K3). No atomics.
__global__ __launch_bounds__(256) void k_fused(
    const unsigned short* __restrict__ Qbf, const unsigned short* __restrict__ wabf,
    const float* __restrict__ Kt, const unsigned short* __restrict__ xbf,
    float* __restrict__ Gp)
{
    __shared__ __align__(16) unsigned short w2s[16 * 516];  // 16 k2-tiles + pad
    __shared__ float red[1024];
    const int flat = blockIdx.x;
    const int bid = (flat & 7) * 72 + (flat >> 3);  // XCD chunk (576 = 8*72)
    const int mc = bid / 6, xt = bid - (bid / 6) * 6;
    const int tid = threadIdx.x;
    const int lane = tid & 63, wv = tid >> 6;
    const int l15 = lane & 15, lg = lane >> 4;

    // GEMM1 A-frags for mtiles {2mc, 2mc+1} — shared by all 16 X
    short8 af[2][3];
#pragma unroll
    for (int mtl = 0; mtl < 2; ++mtl)
#pragma unroll
        for (int kt = 0; kt < 3; ++kt)
            af[mtl][kt] = *(const short8*)(
                Qbf + (size_t)((mc * 2 + mtl) * 3 + kt) * 512 + lane * 8);

#pragma unroll
    for (int xi = 0; xi < 4; ++xi) {
        const int Xl = wv * 4 + xi;                 // wave owns 4 X rows
        const int X = xt * 16 + Xl;
        const unsigned short* bw = wabf + (size_t)X * 3 * 512 + lane * 8;
        const short8 b0 = *(const short8*)(bw);
        const short8 b1 = *(const short8*)(bw + 512);
        const short8 b2 = *(const short8*)(bw + 1024);
#pragma unroll
        for (int mtl = 0; mtl < 2; ++mtl) {
            f32x4 acc = {0.f, 0.f, 0.f, 0.f};
            acc = __builtin_amdgcn_mfma_f32_16x16x32_bf16(af[mtl][0], b0, acc, 0, 0, 0);
            acc = __builtin_amdgcn_mfma_f32_16x16x32_bf16(af[mtl][1], b1, acc, 0, 0, 0);
            acc = __builtin_amdgcn_mfma_f32_16x16x32_bf16(af[mtl][2], b2, acc, 0, 0, 0);
            // C: col(l15)=t, rows m_local = mtl*16 + lg*4 + r
            const int mloc = mtl * 16 + lg * 4;
            const f32x4 kt4 = *(const f32x4*)(Kt + (size_t)X * MM + mc * 32 + mloc);
            ushort4 o;
            o.x = f2b(acc[0] * kt4[0]);
            o.y = f2b(acc[1] * kt4[1]);
            o.z = f2b(acc[2] * kt4[2]);
            o.w = f2b(acc[3] * kt4[3]);
            // scatter to GEMM2-A frag order: tile t=l15, lane (k>>3)*16+Xl, elem k&7
            *(ushort4*)(&w2s[l15 * 516 + ((mloc >> 3) * 16 + Xl) * 8 + (lg & 1) * 4]) = o;
        }
    }
    __syncthreads();

    // GEMM2: wave wv handles t = wv*4..+4; A from LDS, B from global xbf
    f32x4 acc2 = {0.f, 0.f, 0.f, 0.f};
#pragma unroll
    for (int ts = 0; ts < 4; ++ts) {
        const int t = wv * 4 + ts;
        const short8 a2 = *(const short8*)(&w2s[t * 516 + lane * 8]);
        const short8 b2f = *(const short8*)(xbf + ((size_t)(t * SS + mc) * 64 + lane) * 8);
        acc2 = __builtin_amdgcn_mfma_f32_16x16x32_bf16(a2, b2f, acc2, 0, 0, 0);
    }
#pragma unroll
    for (int r = 0; r < 4; ++r)
        red[(wv * 64 + lane) * 4 + r] = acc2[r];
    __syncthreads();
    {   // C layout: col(l&15)=b, row((l>>4)*4+r)=Xl  (verified R11-R20)
        const int Xl = tid >> 4, b = tid & 15;
        const int l = ((Xl >> 2) << 4) | b, r = Xl & 3;
        float s = red[(0 * 64 + l) * 4 + r] + red[(1 * 64 + l) * 4 + r] +
                  red[(2 * 64 + l) * 4 + r] + red[(3 * 64 + l) * 4 + r];
        Gp[(size_t)((xt * 16 + Xl) * BP + b) * NKB + mc] = s;
    }
}

// ---------------------------------------------------------------------------
// K3: final (grid 16 = bp): G[X] = sum_mc Gp[(X*16+bp)*96+mc] (contiguous,
// fixed order), y[bp,c] = sum_X q[bp,X,c]*G[X]. Deterministic plain stores.
__global__ __launch_bounds__(256) void k_final(
    const float* __restrict__ Gp, const float* __restrict__ q,
    float* __restrict__ y)
{
    const int bp = blockIdx.x, tid = threadIdx.x;
    __shared__ float Gh[SS][2];
    __shared__ float G[SS];
    __shared__ float red2[8 * CC];
    if (tid < 192) {
        const int X = tid >> 1, h = tid & 1;
        const float* p = Gp + (size_t)(X * BP + bp) * NKB + h * 48;
        float s = 0.f;
#pragma unroll
        for (int j = 0; j < 12; ++j) {
            f32x4 v4 = *(const f32x4*)(p + j * 4);
            s += v4[0] + v4[1] + v4[2] + v4[3];
        }
        Gh[X][h] = s;
    }
    __syncthreads();
    if (tid < SS) G[tid] = Gh[tid][0] + Gh[tid][1];
    __syncthreads();

    const int c = tid & 31, grp = tid >> 5;
    float acc = 0.f;
#pragma unroll
    for (int k = 0; k < 12; ++k) {
        const int X = grp * 12 + k;
        acc = fmaf(q[((size_t)bp * SS + X) * CC + c], G[X], acc);
    }
    red2[grp * CC + c] = acc;
    __syncthreads();
    if (tid < CC) {
        float s = 0.f;
#pragma unroll
        for (int g8 = 0; g8 < 8; ++g8) s += red2[g8 * CC + tid];
        y[bp * CC + tid] = s;
    }
}

// ---------------------------------------------------------------------------
extern "C" void kernel_launch(void* const* d_in, const int* in_sizes, int n_in,
                              void* d_out, int out_size, void* d_ws, size_t ws_size,
                              hipStream_t stream) {
    const float* x   = (const float*)d_in[0];
    const float* Q   = (const float*)d_in[1];
    const float* K   = (const float*)d_in[2];
    const float* V   = (const float*)d_in[3];
    const float* Aoo = (const float*)d_in[4];
    const float* w   = (const float*)d_in[5];

    char* wsb = (char*)d_ws;                        // 16B-aligned offsets
    float*          Kt   = (float*)(wsb);                     // 1,179,648 B
    float*          Gp   = (float*)(wsb + 1179648);           //   589,824 B
    float*          qb_  = (float*)(wsb + 1769472);           //   196,608 B
    unsigned short* Qbf  = (unsigned short*)(wsb + 1966080);  //   589,824 B
    unsigned short* wabf = (unsigned short*)(wsb + 2555904);  //   294,912 B
    unsigned short* xbf  = (unsigned short*)(wsb + 2850816);  // 1,572,864 B
    float* y = (float*)d_out;                       // total ws: ~4.4 MB

    k_prep<<<dim3(576), 256, 0, stream>>>(x, Q, K, V, Aoo, w, Kt, Qbf, wabf,
                                          xbf, qb_);
    k_fused<<<dim3(576), 256, 0, stream>>>(Qbf, wabf, Kt, xbf, Gp);
    k_final<<<dim3(BP), 256, 0, stream>>>(Gp, qb_, y);
}